// Round 1
// baseline (216.072 us; speedup 1.0000x reference)
//
#include <hip/hip_runtime.h>

#define BB 16
#define NN 4096
#define HQ (BB * NN)        // 65536 queries per direction
#define QT (2 * HQ)         // 131072 total
#define NSLICE 8
#define DBS (NN / NSLICE)   // 512 db points per block
#define WPTS (DBS / 4)      // 128 db points per wave
#define NGRP (WPTS / 4)     // 32 groups of 4 points
#define PQ 16               // queries per lane
#define QW (64 * PQ)        // 1024 queries per block (shared by all 4 waves)
#define NQC (NN / QW)       // 4 query chunks per batch
#define NGROUPS (QT / QW)   // 128 cross-slice reduce groups (1024 queries each)

typedef float v2f __attribute__((ext_vector_type(2)));

// Single fused kernel. Block id bits: slice[0:2], qc[3:4], b[5:8], dir[9].
// 1024 blocks. Main loop identical to the verified 89.1us version:
// all 4 waves share one 1024-query set (PQ=16/lane); each wave owns a
// 128-pt quarter of the block's 512-pt db slice. Per group-of-4 points:
// 3 broadcast ds_read_b128 (36 LDS-cyc, CU-shared) vs 96 pk inst
// (192 SIMD-cyc) -> LDS demand 0.75: VALU-bound.
//
// NEW: the cross-slice reduce + final sum are folded in via the
// last-block-arrival pattern (device-scope atomicAdd + __threadfence,
// G12/G16). grp = bid>>3 = qc + 4*b + 64*dir indexes 1024 contiguous
// queries -- exactly the old chamfer_reduce block partition, and the
// reduce/final bodies are copied verbatim, so the fp summation trees are
// bit-identical (absmax must stay 0.0). Counters are memset to 0 each
// launch by a tiny graph memset node (ws is poisoned between iters).
__global__ __launch_bounds__(256, 4) void chamfer_fused(
    const float* __restrict__ pred, const float* __restrict__ target,
    float* __restrict__ partial, float* __restrict__ bsum,
    int* __restrict__ cnt, float* __restrict__ out) {
  const int bid = blockIdx.x;
  const int slice = bid & (NSLICE - 1);
  const int qc = (bid >> 3) & (NQC - 1);
  const int b = (bid >> 5) & (BB - 1);
  const int dir = bid >> 9;
  const int grp = bid >> 3;  // reduce-group id, 0..127
  const int t = threadIdx.x;
  const int lane = t & 63;
  const int wid = t >> 6;

  // 16 KB: staging uses first 6 KB (3x512 floats); combine reuses all 16 KB.
  __shared__ float smem[4096];
  __shared__ int s_ord, s_ord2;
  __shared__ float red[4];
  float* sTX = smem;
  float* sTY = smem + DBS;
  float* sT2 = smem + 2 * DBS;

  // Stage 512 db points (opposite cloud), 2 per thread, SoA + |t|^2.
  const float2* __restrict__ dsrc = (const float2*)(dir ? pred : target);
  {
    const float4 two = ((const float4*)(dsrc + b * NN + slice * DBS))[t];
    ((float2*)sTX)[t] = {two.x, two.z};
    ((float2*)sTY)[t] = {two.y, two.w};
    ((float2*)sT2)[t] = {__builtin_fmaf(two.x, two.x, two.y * two.y),
                         __builtin_fmaf(two.z, two.z, two.w * two.w)};
  }

  // Load this lane's 16 queries (same set for all 4 waves; L1-hot).
  const float2* __restrict__ qsrc = (const float2*)(dir ? target : pred);
  const int qbase = b * NN + qc * QW + lane;
  v2f nx[PQ], ny[PQ], acc[PQ];
#pragma unroll
  for (int k = 0; k < PQ; ++k) {
    const float2 Q = qsrc[qbase + k * 64];
    const float fx = -2.0f * Q.x, fy = -2.0f * Q.y;
    nx[k] = {fx, fx};
    ny[k] = {fy, fy};
    acc[k] = {3.4e38f, 3.4e38f};
  }
  __syncthreads();

  const float4* __restrict__ gx = (const float4*)sTX + wid * (WPTS / 4);
  const float4* __restrict__ gy = (const float4*)sTY + wid * (WPTS / 4);
  const float4* __restrict__ gs = (const float4*)sT2 + wid * (WPTS / 4);
  for (int g = 0; g < NGRP; ++g) {
    const float4 x4 = gx[g], y4 = gy[g], s4 = gs[g];
    const v2f xlo = {x4.x, x4.y}, xhi = {x4.z, x4.w};
    const v2f ylo = {y4.x, y4.y}, yhi = {y4.z, y4.w};
    const v2f slo = {s4.x, s4.y}, shi = {s4.z, s4.w};
#pragma unroll
    for (int k = 0; k < PQ; ++k) {
      v2f r0 = __builtin_elementwise_fma(ny[k], ylo, slo);
      r0 = __builtin_elementwise_fma(nx[k], xlo, r0);
      acc[k] = __builtin_elementwise_min(acc[k], r0);
      v2f r1 = __builtin_elementwise_fma(ny[k], yhi, shi);
      r1 = __builtin_elementwise_fma(nx[k], xhi, r1);
      acc[k] = __builtin_elementwise_min(acc[k], r1);
    }
  }

  __syncthreads();  // all waves done reading db before smem reuse
  // Per-lane mins -> cmb[k][wid][lane] (lane-contiguous: conflict-free).
#pragma unroll
  for (int k = 0; k < PQ; ++k)
    smem[(k * 4 + wid) * 64 + lane] = fminf(acc[k].x, acc[k].y);
  __syncthreads();

  // Thread t combines the 4 wave-mins for queries k = wid*4 .. wid*4+3.
  const int pbase = slice * QT + dir * HQ + b * NN + qc * QW + lane;
#pragma unroll
  for (int j = 0; j < 4; ++j) {
    const int k = wid * 4 + j;
    const float m = fminf(fminf(smem[(k * 4 + 0) * 64 + lane],
                                smem[(k * 4 + 1) * 64 + lane]),
                          fminf(smem[(k * 4 + 2) * 64 + lane],
                                smem[(k * 4 + 3) * 64 + lane]));
    partial[pbase + k * 64] = m;
  }

  // ---- release this block's partial stores, then signal arrival ----
  __threadfence();   // each thread's stores device-visible (cross-XCD)
  __syncthreads();   // order all threads' fenced stores before t0's atomic
  if (t == 0) s_ord = atomicAdd(&cnt[grp], 1);
  __syncthreads();
  if (s_ord != NSLICE - 1) return;  // 7 of 8 slice-blocks exit here

  // ---- last arriver: cross-slice min for this group's 1024 queries ----
  // (verbatim old chamfer_reduce body, i = grp*256 + t)
  __threadfence();  // acquire: invalidate stale L1/L2 before reading peers
  const float4* __restrict__ partial4 = (const float4*)partial;
  const int i = grp * 256 + t;
  float4 m = partial4[i];
#pragma unroll
  for (int s = 1; s < NSLICE; ++s) {
    const float4 w = partial4[s * (QT / 4) + i];
    m.x = fminf(m.x, w.x);
    m.y = fminf(m.y, w.y);
    m.z = fminf(m.z, w.z);
    m.w = fminf(m.w, w.w);
  }
  const int rdir = i >= (HQ / 4);  // uniform per block
  const int q0 = i * 4 - rdir * HQ;
  const float2* __restrict__ rq = (const float2*)(rdir ? target : pred);
  const float2 Q0 = rq[q0], Q1 = rq[q0 + 1];
  const float2 Q2 = rq[q0 + 2], Q3 = rq[q0 + 3];
  float v = (m.x + __builtin_fmaf(Q0.x, Q0.x, Q0.y * Q0.y)) +
            (m.y + __builtin_fmaf(Q1.x, Q1.x, Q1.y * Q1.y)) +
            (m.z + __builtin_fmaf(Q2.x, Q2.x, Q2.y * Q2.y)) +
            (m.w + __builtin_fmaf(Q3.x, Q3.x, Q3.y * Q3.y));
#pragma unroll
  for (int off = 32; off > 0; off >>= 1) v += __shfl_down(v, off, 64);
  if (lane == 0) red[wid] = v;
  __syncthreads();
  if (t == 0) bsum[grp] = (red[0] + red[1]) + (red[2] + red[3]);

  // ---- publish group sum; last group does the 128-way final sum ----
  __threadfence();
  __syncthreads();
  if (t == 0) s_ord2 = atomicAdd(&cnt[NGROUPS], 1);
  __syncthreads();
  if (s_ord2 != NGROUPS - 1) return;  // 127 of 128 groups exit here

  __threadfence();  // acquire before reading all bsum[]
  if (t < 128) {    // verbatim old chamfer_final (wave0: dir0, wave1: dir1)
    float fv = bsum[t];
#pragma unroll
    for (int off = 32; off > 0; off >>= 1) fv += __shfl_down(fv, off, 64);
    if ((t & 63) == 0) out[t >> 6] = fv * (1.0f / 65536.0f);
  }
}

extern "C" void kernel_launch(void* const* d_in, const int* in_sizes, int n_in,
                              void* d_out, int out_size, void* d_ws, size_t ws_size,
                              hipStream_t stream) {
  const float* pred = (const float*)d_in[0];
  const float* target = (const float*)d_in[1];
  float* out = (float*)d_out;
  float* partial = (float*)d_ws;  // 4 MiB
  float* bsum = (float*)((char*)d_ws + (size_t)NSLICE * QT * 4);  // 512 B
  int* cnt = (int*)((char*)d_ws + (size_t)NSLICE * QT * 4 + NGROUPS * 4);

  // ws is poisoned between iterations: zero the 129 arrival counters.
  // Async memset is stream-ordered and graph-capturable (no sync APIs).
  hipMemsetAsync(cnt, 0, (NGROUPS + 1) * sizeof(int), stream);
  chamfer_fused<<<2 * BB * NQC * NSLICE, 256, 0, stream>>>(pred, target,
                                                           partial, bsum, cnt,
                                                           out);
}

// Round 2
// 91.044 us; speedup vs baseline: 2.3733x; 2.3733x over previous
//
#include <hip/hip_runtime.h>

#define BB 16
#define NN 4096
#define HQ (BB * NN)        // 65536 queries per direction
#define QT (2 * HQ)         // 131072 total
#define NSLICE 8
#define DBS (NN / NSLICE)   // 512 db points per block
#define WPTS (DBS / 4)      // 128 db points per wave
#define NGRP (WPTS / 4)     // 32 groups of 4 points
#define PQ 16               // queries per lane
#define QW (64 * PQ)        // 1024 queries per block (shared by all 4 waves)
#define NQC (NN / QW)       // 4 query chunks per batch
#define NGROUPS (QT / QW)   // 128 cross-slice reduce groups (1024 queries each)

typedef float v2f __attribute__((ext_vector_type(2)));

// Single fused kernel, NO __threadfence (agent fences = buffer_wbl2 +
// buffer_inv = full per-XCD L2 flush; 1024 of them cost ~190us in R1).
// Cross-block communication instead uses per-access agent-scope relaxed
// atomics: stores lower to global_store sc1 (write-through past the
// non-coherent per-XCD L2 -> visible at LLC), loads to global_load sc1
// (bypass stale L1/L2 lines, incl. poison-fill residue from other XCDs).
// Ordering: compiler drains s_waitcnt vmcnt(0) before every s_barrier
// (m97-verified), so  sc1-stores -> __syncthreads -> t0 atomicAdd  is a
// release, and  s_ord==7 -> sc1-loads  is the matching acquire.
// Reduce/final bodies keep the exact fp trees of the verified 89.1us
// 3-kernel version (absmax must stay 0.0).
__global__ __launch_bounds__(256, 4) void chamfer_fused(
    const float* __restrict__ pred, const float* __restrict__ target,
    float* __restrict__ partial, float* __restrict__ bsum,
    int* __restrict__ cnt, float* __restrict__ out) {
  const int bid = blockIdx.x;
  const int slice = bid & (NSLICE - 1);
  const int qc = (bid >> 3) & (NQC - 1);
  const int b = (bid >> 5) & (BB - 1);
  const int dir = bid >> 9;
  const int grp = bid >> 3;  // reduce-group id, 0..127
  const int t = threadIdx.x;
  const int lane = t & 63;
  const int wid = t >> 6;

  // 16 KB: staging uses first 6 KB (3x512 floats); combine reuses all 16 KB.
  __shared__ float smem[4096];
  __shared__ int s_ord, s_ord2;
  __shared__ float red[4];
  float* sTX = smem;
  float* sTY = smem + DBS;
  float* sT2 = smem + 2 * DBS;

  // Stage 512 db points (opposite cloud), 2 per thread, SoA + |t|^2.
  const float2* __restrict__ dsrc = (const float2*)(dir ? pred : target);
  {
    const float4 two = ((const float4*)(dsrc + b * NN + slice * DBS))[t];
    ((float2*)sTX)[t] = {two.x, two.z};
    ((float2*)sTY)[t] = {two.y, two.w};
    ((float2*)sT2)[t] = {__builtin_fmaf(two.x, two.x, two.y * two.y),
                         __builtin_fmaf(two.z, two.z, two.w * two.w)};
  }

  // Load this lane's 16 queries (same set for all 4 waves; L1-hot).
  const float2* __restrict__ qsrc = (const float2*)(dir ? target : pred);
  const int qbase = b * NN + qc * QW + lane;
  v2f nx[PQ], ny[PQ], acc[PQ];
#pragma unroll
  for (int k = 0; k < PQ; ++k) {
    const float2 Q = qsrc[qbase + k * 64];
    const float fx = -2.0f * Q.x, fy = -2.0f * Q.y;
    nx[k] = {fx, fx};
    ny[k] = {fy, fy};
    acc[k] = {3.4e38f, 3.4e38f};
  }
  __syncthreads();

  const float4* __restrict__ gx = (const float4*)sTX + wid * (WPTS / 4);
  const float4* __restrict__ gy = (const float4*)sTY + wid * (WPTS / 4);
  const float4* __restrict__ gs = (const float4*)sT2 + wid * (WPTS / 4);
  for (int g = 0; g < NGRP; ++g) {
    const float4 x4 = gx[g], y4 = gy[g], s4 = gs[g];
    const v2f xlo = {x4.x, x4.y}, xhi = {x4.z, x4.w};
    const v2f ylo = {y4.x, y4.y}, yhi = {y4.z, y4.w};
    const v2f slo = {s4.x, s4.y}, shi = {s4.z, s4.w};
#pragma unroll
    for (int k = 0; k < PQ; ++k) {
      v2f r0 = __builtin_elementwise_fma(ny[k], ylo, slo);
      r0 = __builtin_elementwise_fma(nx[k], xlo, r0);
      acc[k] = __builtin_elementwise_min(acc[k], r0);
      v2f r1 = __builtin_elementwise_fma(ny[k], yhi, shi);
      r1 = __builtin_elementwise_fma(nx[k], xhi, r1);
      acc[k] = __builtin_elementwise_min(acc[k], r1);
    }
  }

  __syncthreads();  // all waves done reading db before smem reuse
  // Per-lane mins -> cmb[k][wid][lane] (lane-contiguous: conflict-free).
#pragma unroll
  for (int k = 0; k < PQ; ++k)
    smem[(k * 4 + wid) * 64 + lane] = fminf(acc[k].x, acc[k].y);
  __syncthreads();

  // Thread t combines the 4 wave-mins for queries k = wid*4 .. wid*4+3,
  // stores with agent-scope (sc1, write-through to LLC).
  const int pbase = slice * QT + dir * HQ + b * NN + qc * QW + lane;
#pragma unroll
  for (int j = 0; j < 4; ++j) {
    const int k = wid * 4 + j;
    const float m = fminf(fminf(smem[(k * 4 + 0) * 64 + lane],
                                smem[(k * 4 + 1) * 64 + lane]),
                          fminf(smem[(k * 4 + 2) * 64 + lane],
                                smem[(k * 4 + 3) * 64 + lane]));
    __hip_atomic_store(&partial[pbase + k * 64], m, __ATOMIC_RELAXED,
                       __HIP_MEMORY_SCOPE_AGENT);
  }

  // Release: barrier drains vmcnt(0) -> all sc1 stores are at LLC.
  __syncthreads();
  if (t == 0) s_ord = atomicAdd(&cnt[grp], 1);  // device-scope by default
  __syncthreads();
  if (s_ord != NSLICE - 1) return;  // 7 of 8 slice-blocks exit here

  // ---- last arriver: cross-slice min for this group's 1024 queries ----
  // Same fp tree as the verified chamfer_reduce (per-component fminf over
  // ascending s), but via sc1 scalar loads (L1/L2 may hold stale poison).
  const int i = grp * 256 + t;
  const int pidx = grp * QW + 4 * t;
  float mx = __hip_atomic_load(&partial[pidx + 0], __ATOMIC_RELAXED,
                               __HIP_MEMORY_SCOPE_AGENT);
  float my = __hip_atomic_load(&partial[pidx + 1], __ATOMIC_RELAXED,
                               __HIP_MEMORY_SCOPE_AGENT);
  float mz = __hip_atomic_load(&partial[pidx + 2], __ATOMIC_RELAXED,
                               __HIP_MEMORY_SCOPE_AGENT);
  float mw = __hip_atomic_load(&partial[pidx + 3], __ATOMIC_RELAXED,
                               __HIP_MEMORY_SCOPE_AGENT);
#pragma unroll
  for (int s = 1; s < NSLICE; ++s) {
    mx = fminf(mx, __hip_atomic_load(&partial[s * QT + pidx + 0],
                                     __ATOMIC_RELAXED,
                                     __HIP_MEMORY_SCOPE_AGENT));
    my = fminf(my, __hip_atomic_load(&partial[s * QT + pidx + 1],
                                     __ATOMIC_RELAXED,
                                     __HIP_MEMORY_SCOPE_AGENT));
    mz = fminf(mz, __hip_atomic_load(&partial[s * QT + pidx + 2],
                                     __ATOMIC_RELAXED,
                                     __HIP_MEMORY_SCOPE_AGENT));
    mw = fminf(mw, __hip_atomic_load(&partial[s * QT + pidx + 3],
                                     __ATOMIC_RELAXED,
                                     __HIP_MEMORY_SCOPE_AGENT));
  }
  const int rdir = i >= (HQ / 4);  // uniform per block
  const int q0 = i * 4 - rdir * HQ;
  const float2* __restrict__ rq = (const float2*)(rdir ? target : pred);
  const float2 Q0 = rq[q0], Q1 = rq[q0 + 1];
  const float2 Q2 = rq[q0 + 2], Q3 = rq[q0 + 3];
  float v = (mx + __builtin_fmaf(Q0.x, Q0.x, Q0.y * Q0.y)) +
            (my + __builtin_fmaf(Q1.x, Q1.x, Q1.y * Q1.y)) +
            (mz + __builtin_fmaf(Q2.x, Q2.x, Q2.y * Q2.y)) +
            (mw + __builtin_fmaf(Q3.x, Q3.x, Q3.y * Q3.y));
#pragma unroll
  for (int off = 32; off > 0; off >>= 1) v += __shfl_down(v, off, 64);
  if (lane == 0) red[wid] = v;
  __syncthreads();
  if (t == 0)
    __hip_atomic_store(&bsum[grp], (red[0] + red[1]) + (red[2] + red[3]),
                       __ATOMIC_RELAXED, __HIP_MEMORY_SCOPE_AGENT);

  // Release the bsum store (barrier drains t0's vmcnt), then signal.
  __syncthreads();
  if (t == 0) s_ord2 = atomicAdd(&cnt[NGROUPS], 1);
  __syncthreads();
  if (s_ord2 != NGROUPS - 1) return;  // 127 of 128 groups exit here

  if (t < 128) {  // verbatim old chamfer_final (wave0: dir0, wave1: dir1)
    float fv = __hip_atomic_load(&bsum[t], __ATOMIC_RELAXED,
                                 __HIP_MEMORY_SCOPE_AGENT);
#pragma unroll
    for (int off = 32; off > 0; off >>= 1) fv += __shfl_down(fv, off, 64);
    if ((t & 63) == 0) out[t >> 6] = fv * (1.0f / 65536.0f);
  }
}

extern "C" void kernel_launch(void* const* d_in, const int* in_sizes, int n_in,
                              void* d_out, int out_size, void* d_ws, size_t ws_size,
                              hipStream_t stream) {
  const float* pred = (const float*)d_in[0];
  const float* target = (const float*)d_in[1];
  float* out = (float*)d_out;
  float* partial = (float*)d_ws;  // 4 MiB
  float* bsum = (float*)((char*)d_ws + (size_t)NSLICE * QT * 4);  // 512 B
  int* cnt = (int*)((char*)d_ws + (size_t)NSLICE * QT * 4 + NGROUPS * 4);

  // ws is poisoned between iterations: zero the 129 arrival counters.
  // Async memset is stream-ordered and graph-capturable (no sync APIs).
  hipMemsetAsync(cnt, 0, (NGROUPS + 1) * sizeof(int), stream);
  chamfer_fused<<<2 * BB * NQC * NSLICE, 256, 0, stream>>>(pred, target,
                                                           partial, bsum, cnt,
                                                           out);
}